// Round 17
// baseline (3100.681 us; speedup 1.0000x reference)
//
#include <hip/hip_runtime.h>
#include <hip/hip_bf16.h>

// ---------------------------------------------------------------------------
// K0: prep: cbt[d][j] = cb[j][d] (transpose), cnorm[j] = numpy-fp32 sum cb[j][d]^2
// (byte-identical to the R6..R12 passing version)
// ---------------------------------------------------------------------------
__global__ __launch_bounds__(256) void prep_k(const float* __restrict__ cb,
                                              float* __restrict__ cbt,
                                              float* __restrict__ cnorm) {
  __shared__ float sv[256];
  int j = blockIdx.x, c = threadIdx.x;
  float v = cb[j * 256 + c];
  cbt[c * 1024 + j] = v;
  sv[c] = v;
  __syncthreads();
  if (c == 0) {
#pragma clang fp contract(off)
    float halves[2];
    for (int h = 0; h < 2; h++) {
      const float* a = sv + h * 128;
      float r[8];
      for (int k = 0; k < 8; k++) r[k] = a[k] * a[k];
      for (int i0 = 8; i0 < 128; i0 += 8)
        for (int k = 0; k < 8; k++) {
          float z = a[i0 + k];
          r[k] += z * z;
        }
      halves[h] = ((r[0] + r[1]) + (r[2] + r[3])) + ((r[4] + r[5]) + (r[6] + r[7]));
    }
    cnorm[j] = halves[0] + halves[1];
  }
}

// ---------------------------------------------------------------------------
// K1: conv1+conv2 — R17: R11 2x2-quad structure (1417us, VALUBusy 73%,
// VGPR 104) + T14 STAGE SPLIT. R10's immediate-write staging exposed the w2
// global-load latency (~300-500cy) BEFORE each compute phase: stage did
// load -> ds_write (vmcnt wait) -> compute. Split: STAGE_LOAD (issue global
// loads + conv1 into regs) before compute, STAGE_WRITE (LDS writes) after
// -> the load latency hides under 544 FMAs. q0/q1/spv live across compute =
// +10 regs -> ~114, inside the 128 cliff (24 regs headroom measured).
// Race invariant unchanged: writes to buf cur^1 complete before the barrier;
// reads of cur^1 only after it (same as R0/R1 which passed). Same loads,
// same conv1 exprs, same FMA order -> numerics unchanged.
// ---------------------------------------------------------------------------
__global__ __launch_bounds__(256) void conv12_k(const float* __restrict__ x,
                                                const float* __restrict__ w1,
                                                const float* __restrict__ b1,
                                                const float* __restrict__ w2,
                                                const float* __restrict__ b2,
                                                float* __restrict__ z_e) {
  __shared__ float xt[38][40];     // x tile (fp32, zero-padded), 38x38 used
  __shared__ float sp[2][18][20];  // conv1 output tile (18x18 used), dbuf
  __shared__ float sw[2][2176];    // conv2 weights: 16 grp x 8 co x 16, stride 136
  int t = threadIdx.x;
  int b = blockIdx.y;
  int co0 = blockIdx.z * 128;      // co half
  int oh0 = (blockIdx.x >> 3) * 8, ow0 = (blockIdx.x & 7) * 8;  // 8x8 tile
  int ihb = 2 * oh0 - 1, iwb = 2 * ow0 - 1;
  int xrb = 2 * ihb - 1, xcb = 2 * iwb - 1;
  int pg = t & 15, cog = t >> 4;   // pg: 4x4 grid of 2x2-output quads
  int qy = pg >> 2, qx = pg & 3;
  int prow0 = 4 * qy, pcol0 = 4 * qx;  // p-window base in sp (16B-aligned col)

  // sp staging points: 18x18 = 324; thread t handles t, and t+256 if t<68
  int r0s = t / 18, c0s = t - r0s * 18;
  bool has1 = (t < 68);
  int i1 = t + 256;
  int r1s = i1 / 18, c1s = i1 - r1s * 18;
  bool inb0 = (ihb + r0s >= 0) && (ihb + r0s < 128) && (iwb + c0s >= 0) && (iwb + c0s < 128);
  bool inb1 = has1 && (ihb + r1s >= 0) && (ihb + r1s < 128) && (iwb + c1s >= 0) && (iwb + c1s < 128);

  // w2 staging role: two threads per co row (8 floats each), 128 co
  int scl = t >> 1;                 // co_local 0..127
  int shalf = t & 1;                // which 8-tap half
  int sw_off = (scl >> 3) * 136 + (scl & 7) * 16 + shalf * 8;
  const float* w2base = w2 + ((co0 + scl) * 256) * 16 + shalf * 8;

  // ---- stage x tile (38x38 used) ----
  const float* xb = x + b * 65536;
  for (int i = t; i < 1444; i += 256) {
    int rr = i / 38, cc = i - rr * 38;
    int gr = xrb + rr, gc = xcb + cc;
    float v = 0.f;
    if (gr >= 0 && gr < 256 && gc >= 0 && gc < 256) v = xb[gr * 256 + gc];
    xt[rr][cc] = v;
  }
  __syncthreads();

  float4 q0, q1;                 // staged w2 taps for next ci (live across compute)
  float spv0 = 0.f, spv1 = 0.f;  // staged conv1 outputs for next ci

  // T14 split: issue global loads + conv1 (regs only) — no LDS writes here
  auto stage_load = [&](int ci) {
    const float4* src = (const float4*)(w2base + ci * 16);
    q0 = src[0];
    q1 = src[1];
    {
      float w1v[16];  // lane-uniform -> scalar regs
#pragma unroll
      for (int k = 0; k < 16; k++) w1v[k] = w1[ci * 16 + k];
      float b1v = b1[ci];
      {
        float a = b1v;
#pragma unroll
        for (int kh = 0; kh < 4; kh++)
#pragma unroll
          for (int kw = 0; kw < 4; kw++)
            a += xt[2 * r0s + kh][2 * c0s + kw] * w1v[kh * 4 + kw];
        spv0 = inb0 ? fmaxf(a, 0.f) : 0.f;
      }
      if (has1) {
        float a = b1v;
#pragma unroll
        for (int kh = 0; kh < 4; kh++)
#pragma unroll
          for (int kw = 0; kw < 4; kw++)
            a += xt[2 * r1s + kh][2 * c1s + kw] * w1v[kh * 4 + kw];
        spv1 = inb1 ? fmaxf(a, 0.f) : 0.f;
      }
    }
  };

  // T14 split: LDS writes only (after compute, before barrier)
  auto stage_write = [&](int bf) {
    sp[bf][r0s][c0s] = spv0;
    if (has1) sp[bf][r1s][c1s] = spv1;
    float4* dst = (float4*)&sw[bf][sw_off];
    dst[0] = q0;
    dst[1] = q1;
  };

  float accO[8][4];
#pragma unroll
  for (int i = 0; i < 8; i++)
#pragma unroll
    for (int e = 0; e < 4; e++) accO[i][e] = 0.f;

  // prologue: stage ci=0 into buffer 0
  stage_load(0);
  stage_write(0);
  __syncthreads();

  for (int cio = 0; cio < 16; cio++) {
    float accI[8][4];
#pragma unroll
    for (int i = 0; i < 8; i++)
#pragma unroll
      for (int e = 0; e < 4; e++) accI[i][e] = 0.f;
    for (int cii = 0; cii < 16; cii++) {
      int ci = cio * 16 + cii;
      int cur = ci & 1;
      if (ci < 255) stage_load(ci + 1);  // issue next-ci loads early (T14)
      // ---- this quad's input patch: sp rows prow0..+5, cols pcol0..+5 ----
      float p[6][6];
#pragma unroll
      for (int rr = 0; rr < 6; rr++) {
        float4 v0 = *(const float4*)&sp[cur][prow0 + rr][pcol0];      // 16B-aligned
        float2 v1 = *(const float2*)&sp[cur][prow0 + rr][pcol0 + 4];  // 8B-aligned
        p[rr][0] = v0.x; p[rr][1] = v0.y; p[rr][2] = v0.z; p[rr][3] = v0.w;
        p[rr][4] = v1.x; p[rr][5] = v1.y;
      }
#pragma unroll
      for (int cc = 0; cc < 8; cc++) {
        const float4* wq = (const float4*)&sw[cur][cog * 136 + cc * 16];
        float s00 = 0.f, s01 = 0.f, s10 = 0.f, s11 = 0.f;
#pragma unroll
        for (int kh = 0; kh < 4; kh++) {
          float4 w4 = wq[kh];
          // per-output tap order: kh outer, kw inner (original sequence)
          s00 += p[kh][0] * w4.x;
          s00 += p[kh][1] * w4.y;
          s00 += p[kh][2] * w4.z;
          s00 += p[kh][3] * w4.w;
          s01 += p[kh][2] * w4.x;
          s01 += p[kh][3] * w4.y;
          s01 += p[kh][4] * w4.z;
          s01 += p[kh][5] * w4.w;
          s10 += p[kh + 2][0] * w4.x;
          s10 += p[kh + 2][1] * w4.y;
          s10 += p[kh + 2][2] * w4.z;
          s10 += p[kh + 2][3] * w4.w;
          s11 += p[kh + 2][2] * w4.x;
          s11 += p[kh + 2][3] * w4.y;
          s11 += p[kh + 2][4] * w4.z;
          s11 += p[kh + 2][5] * w4.w;
        }
        accI[cc][0] += s00;
        accI[cc][1] += s01;
        accI[cc][2] += s10;
        accI[cc][3] += s11;
      }
      if (ci < 255) stage_write(cur ^ 1);  // LDS write after compute (T14)
      __syncthreads();                     // single barrier per ci-step
    }
#pragma unroll
    for (int cc = 0; cc < 8; cc++)
#pragma unroll
      for (int e = 0; e < 4; e++) accO[cc][e] += accI[cc][e];
  }

  // ---- write z_e (fp32, exact) to global ws ----
#pragma unroll
  for (int cc = 0; cc < 8; cc++) {
    int co = co0 + cog * 8 + cc;
    float bv = b2[co];
    float* zeb = z_e + (b * 256 + co) * 4096;
#pragma unroll
    for (int dy = 0; dy < 2; dy++)
#pragma unroll
      for (int dx = 0; dx < 2; dx++) {
        int oh = oh0 + 2 * qy + dy, ow = ow0 + 2 * qx + dx;
        zeb[oh * 64 + ow] = fmaxf(accO[cc][dy * 2 + dx] + bv, 0.f);
      }
  }
}

// ---------------------------------------------------------------------------
// K2: VQ standalone (byte-identical to R12's passing vq_k).
// ---------------------------------------------------------------------------
__global__ __launch_bounds__(256) void vq_k(const float* __restrict__ z_e,
                                            const float* __restrict__ cb,
                                            const float* __restrict__ cbt,
                                            const float* __restrict__ cnorm,
                                            float* __restrict__ zq) {
  __shared__ float ztT[256][64];
  int t = threadIdx.x;
  int b = blockIdx.y;
  int hw0 = blockIdx.x * 64;
  int lane = t & 63, pg = t >> 6, pbase = pg * 16;

  // ---- fill ztT[d][p] from z_e (coalesced) ----
  const float* zb = z_e + b * 1048576;
  for (int k = 0; k < 64; k++) {
    int dd = pg * 64 + k;
    ztT[dd][lane] = zb[dd * 4096 + hw0 + lane];
  }
  __syncthreads();

  // ---- znorm: numpy pairwise fp32 sum of z^2, point = lane ----
  float myzn;
  {
#pragma clang fp contract(off)
    float halves[2];
    for (int h = 0; h < 2; h++) {
      int base = h * 128;
      float r[8];
#pragma unroll
      for (int k = 0; k < 8; k++) {
        float z = ztT[base + k][lane];
        r[k] = z * z;
      }
      for (int i0 = 8; i0 < 128; i0 += 8)
#pragma unroll
        for (int k = 0; k < 8; k++) {
          float z = ztT[base + i0 + k][lane];
          r[k] += z * z;
        }
      halves[h] = ((r[0] + r[1]) + (r[2] + r[3])) + ((r[4] + r[5]) + (r[6] + r[7]));
    }
    myzn = halves[0] + halves[1];
  }
  float znp[16];
#pragma unroll
  for (int i = 0; i < 16; i++) znp[i] = __shfl(myzn, pbase + i, 64);

  // ---- VQ scores: 2 codes/lane/pass x 8 passes; fp32 absorbed formula ----
  float best[16];
  int bidx[16];
#pragma unroll
  for (int i = 0; i < 16; i++) {
    best[i] = 3.4e38f;
    bidx[i] = 0;
  }
  for (int pass = 0; pass < 8; pass++) {
    int j1 = pass * 128 + lane;
    float a1[16], a2[16];
#pragma unroll
    for (int i = 0; i < 16; i++) {
      a1[i] = 0.f;
      a2[i] = 0.f;
    }
    for (int d0 = 0; d0 < 256; d0 += 8) {
      float c1[8], c2[8];
#pragma unroll
      for (int k = 0; k < 8; k++) {
        c1[k] = cbt[(d0 + k) * 1024 + j1];
        c2[k] = cbt[(d0 + k) * 1024 + j1 + 64];
      }
#pragma unroll
      for (int i = 0; i < 16; i++) {
        int pp = pbase + i;
#pragma unroll
        for (int k = 0; k < 8; k++) {
          float z = ztT[d0 + k][pp];
          a1[i] = __builtin_fmaf(z, c1[k], a1[i]);
          a2[i] = __builtin_fmaf(z, c2[k], a2[i]);
        }
      }
    }
    float cn1 = cnorm[j1], cn2 = cnorm[j1 + 64];
    {
#pragma clang fp contract(off)
#pragma unroll
      for (int i = 0; i < 16; i++) {
        float t1 = znp[i] - 2.0f * a1[i];
        float s1 = t1 + cn1;
        if (s1 < best[i]) {
          best[i] = s1;
          bidx[i] = j1;
        }
        float t2 = znp[i] - 2.0f * a2[i];
        float s2 = t2 + cn2;
        if (s2 < best[i]) {
          best[i] = s2;
          bidx[i] = j1 + 64;
        }
      }
    }
  }
#pragma unroll
  for (int off = 1; off < 64; off <<= 1) {
#pragma unroll
    for (int i = 0; i < 16; i++) {
      float ov = __shfl_xor(best[i], off, 64);
      int oi = __shfl_xor(bidx[i], off, 64);
      if (ov < best[i] || (ov == best[i] && oi < bidx[i])) {
        best[i] = ov;
        bidx[i] = oi;
      }
    }
  }
  __syncthreads();
  int* sidx = (int*)&ztT[0][0];
  if (lane == 0) {
#pragma unroll
    for (int i = 0; i < 16; i++) sidx[pbase + i] = bidx[i];
  }
  __syncthreads();

  // ---- gather z_q: exact fp32 codebook rows (coalesced writes) ----
  int p = t & 63, c4 = t >> 6;
  int jw = sidx[p];
  float* zqb = zq + b * 1048576;
  for (int k = 0; k < 64; k++) {
    int c = c4 * 64 + k;
    zqb[c * 4096 + hw0 + p] = cb[jw * 256 + c];
  }
}

// ---------------------------------------------------------------------------
// K3: convT1 — R16 version, byte-identical (best: dropped below 1417us).
// LDS inputs + LDS broadcast weights, direct-quad FMAs (no wv[16] copy),
// __launch_bounds__(256,2): 128 arch + 128 acc = 256/wave = 2 waves/SIMD.
// DO NOT add registers here — zero headroom under the forced bound.
// ---------------------------------------------------------------------------
__global__ __launch_bounds__(256, 2) void convt1_k(const float* __restrict__ zq,
                                                   const float* __restrict__ w,
                                                   const float* __restrict__ bias,
                                                   float* __restrict__ d) {
  __shared__ float zt[2][18][20];  // zq tile dbuf (18x18 used, pad 20)
  __shared__ float sw[2][512];     // weights dbuf: 32 co x 16 taps
  int t = threadIdx.x;
  int b = blockIdx.z;
  int co0 = blockIdx.y * 32;
  int oh0 = (blockIdx.x >> 2) * 32, ow0 = (blockIdx.x & 3) * 32;
  int wid8 = __builtin_amdgcn_readfirstlane(t >> 6) * 8;
  int lane = t & 63;
  int ty = lane >> 3, tx = lane & 7;
  int ihb = oh0 / 2 - 1, iwb = ow0 / 2 - 1;  // tile covers input rows ihb..ihb+17
  const float* zqb = zq + b * 1048576;

  // staging points: 18x18 = 324; thread t handles t, and t+256 if t<68
  int r0s = t / 18, c0s = t - r0s * 18;
  bool has1 = (t < 68);
  int i1 = t + 256;
  int r1s = i1 / 18, c1s = i1 - r1s * 18;
  int g0r = ihb + r0s, g0c = iwb + c0s;
  int g1r = ihb + r1s, g1c = iwb + c1s;
  bool ok0 = (g0r >= 0) && (g0r < 64) && (g0c >= 0) && (g0c < 64);
  bool ok1 = has1 && (g1r >= 0) && (g1r < 64) && (g1c >= 0) && (g1c < 64);
  int off0 = g0r * 64 + g0c, off1 = g1r * 64 + g1c;

  auto stage = [&](int ci, int bf) {
    const float* zc = zqb + ci * 4096;
    zt[bf][r0s][c0s] = ok0 ? zc[off0] : 0.f;
    if (has1) zt[bf][r1s][c1s] = ok1 ? zc[off1] : 0.f;
    if (t < 128) {
      const float4* wsrc = (const float4*)(w + (ci * 256 + co0) * 16);
      *((float4*)&sw[bf][t * 4]) = wsrc[t];
    }
  };

  float acc[8][16];
#pragma unroll
  for (int i = 0; i < 8; i++)
#pragma unroll
    for (int e = 0; e < 16; e++) acc[i][e] = 0.f;

  stage(0, 0);
  __syncthreads();

  for (int ci = 0; ci < 256; ci++) {
    int cur = ci & 1;
    if (ci < 255) stage(ci + 1, cur ^ 1);  // stage next ci (other dbuf half)
    // ---- this lane's input patch from LDS: rows 2ty.., cols 2tx.. ----
    float p[4][4];
#pragma unroll
    for (int r = 0; r < 4; r++)
#pragma unroll
      for (int c = 0; c < 4; c++)
        p[r][c] = zt[cur][2 * ty + r][2 * tx + c];
#pragma unroll
    for (int cc = 0; cc < 8; cc++) {
      // wave-uniform LDS address -> broadcast b128 reads, conflict-free
      const float4* wq = (const float4*)&sw[cur][(wid8 + cc) * 16];
      float4 q0 = wq[0], q1 = wq[1], q2 = wq[2], q3 = wq[3];
#pragma unroll
      for (int dy = 0; dy < 4; dy++) {
        int rA = ((dy + 1) >> 1) + 1, rB = rA - 1;
        // khA = 1-(dy&1): quad q1 (dy even) or q0 (dy odd); khB = khA+2
        float4 qA = (dy & 1) ? q0 : q1;
        float4 qB = (dy & 1) ? q2 : q3;
#pragma unroll
        for (int dx = 0; dx < 4; dx++) {
          int cA = ((dx + 1) >> 1) + 1, cB = cA - 1;
          // kwA = 1-(dx&1): comp .y (dx even) or .x (dx odd); kwB = kwA+2
          float wAA = (dx & 1) ? qA.x : qA.y;
          float wAB = (dx & 1) ? qA.z : qA.w;
          float wBA = (dx & 1) ? qB.x : qB.y;
          float wBB = (dx & 1) ? qB.z : qB.w;
          float s = p[rA][cA] * wAA;
          s += p[rA][cB] * wAB;
          s += p[rB][cA] * wBA;
          s += p[rB][cB] * wBB;
          acc[cc][dy * 4 + dx] += s;
        }
      }
    }
    __syncthreads();  // stage-writes for ci+1 complete before next read
  }
#pragma unroll
  for (int cc = 0; cc < 8; cc++) {
    int co = co0 + wid8 + cc;
    float bv = bias[co];
    float* db = d + (b * 256 + co) * 16384;
#pragma unroll
    for (int dy = 0; dy < 4; dy++)
#pragma unroll
      for (int dx = 0; dx < 4; dx++) {
        int oh = oh0 + 4 * ty + dy, ow = ow0 + 4 * tx + dx;
        db[oh * 128 + ow] = fmaxf(acc[cc][dy * 4 + dx] + bv, 0.f);
      }
  }
}

// ---------------------------------------------------------------------------
// K4: convT2 FULL BATCH — 2x2-tile version (grid 512), byte-identical to the
// R11 passing build.
// ---------------------------------------------------------------------------
__global__ __launch_bounds__(256) void convt2_k(const float* __restrict__ d,
                                                const float* __restrict__ w,
                                                const float* __restrict__ bias,
                                                float* __restrict__ out) {
  int idx = blockIdx.x * 256 + threadIdx.x;  // < 131072
  int j = idx & 127;          // ow / 2
  int i = (idx >> 7) & 127;   // oh / 2
  int b = idx >> 14;
  bool rT = (i > 0), rB = (i < 127), cL = (j > 0), cR = (j < 127);
  const float* db = d + b * 4194304;
  int r0 = (i - 1) * 128 + j, r1 = i * 128 + j, r2 = (i + 1) * 128 + j;
  float bv = bias[0];
  float a00 = bv, a01 = bv, a10 = bv, a11 = bv;
#pragma unroll 2
  for (int ci = 0; ci < 256; ci++) {
    const float* dc = db + ci * 16384;
    const float* wc = w + ci * 16;  // wave-uniform -> SGPRs
    float p11 = dc[r1];
    float p10 = cL ? dc[r1 - 1] : 0.f;
    float p12 = cR ? dc[r1 + 1] : 0.f;
    float p01 = rT ? dc[r0] : 0.f;
    float p00 = (rT && cL) ? dc[r0 - 1] : 0.f;
    float p02 = (rT && cR) ? dc[r0 + 1] : 0.f;
    float p21 = rB ? dc[r2] : 0.f;
    float p20 = (rB && cL) ? dc[r2 - 1] : 0.f;
    float p22 = (rB && cR) ? dc[r2 + 1] : 0.f;
    float wv[16];
#pragma unroll
    for (int k = 0; k < 16; k++) wv[k] = wc[k];
    // (oh=2i, ow=2j):   khA=1 khB=3 kwA=1 kwB=3; A-row=i, B-row=i-1
    {
      float s = 0.f;
      s += p11 * wv[5];
      if (cL) s += p10 * wv[7];
      if (rT) s += p01 * wv[13];
      if (rT && cL) s += p00 * wv[15];
      a00 += s;
    }
    // (oh=2i, ow=2j+1): khA=1 khB=3 kwA=0 kwB=2; A-col=j+1, B-col=j
    {
      float s = 0.f;
      if (cR) s += p12 * wv[4];
      s += p11 * wv[6];
      if (rT && cR) s += p02 * wv[12];
      if (rT) s += p01 * wv[14];
      a01 += s;
    }
    // (oh=2i+1, ow=2j): khA=0 khB=2 kwA=1 kwB=3; A-row=i+1, B-row=i
    {
      float s = 0.f;
      if (rB) s += p21 * wv[1];
      if (rB && cL) s += p20 * wv[3];
      s += p11 * wv[9];
      if (cL) s += p10 * wv[11];
      a10 += s;
    }
    // (oh=2i+1, ow=2j+1): khA=0 khB=2 kwA=0 kwB=2
    {
      float s = 0.f;
      if (rB && cR) s += p22 * wv[0];
      if (rB) s += p21 * wv[2];
      if (cR) s += p12 * wv[8];
      s += p11 * wv[10];
      a11 += s;
    }
  }
  int ob = b * 65536 + (2 * i) * 256 + 2 * j;
  *(float2*)&out[ob] = make_float2(a00, a01);
  *(float2*)&out[ob + 256] = make_float2(a10, a11);
}

// ---------------------------------------------------------------------------
extern "C" void kernel_launch(void* const* d_in, const int* in_sizes, int n_in,
                              void* d_out, int out_size, void* d_ws, size_t ws_size,
                              hipStream_t stream) {
  const float* x = (const float*)d_in[0];
  const float* e1w = (const float*)d_in[1];
  const float* e1b = (const float*)d_in[2];
  const float* e2w = (const float*)d_in[3];
  const float* e2b = (const float*)d_in[4];
  const float* cb = (const float*)d_in[5];
  const float* d1w = (const float*)d_in[6];
  const float* d1b = (const float*)d_in[7];
  const float* d2w = (const float*)d_in[8];
  const float* d2b = (const float*)d_in[9];

  // ws layout (135,270,400 B total — same proven footprint as R6..R12):
  //   cbt   fp32 [0, 1048576)              codebook transpose [d][j]
  //   cnorm fp32 [1048576, 1052672)        numpy-fp32 |c_j|^2
  //   z_e   fp32 [1052672, 34607104)       encoder output (dead after vq_k)
  //   dbuf  fp32 [1052672, 135270400)      decoder intermediate (OVERLAPS z_e;
  //                                        written by convt1_k after vq_k)
  char* ws = (char*)d_ws;
  float* cbt = (float*)ws;
  float* cnorm = (float*)(ws + 1048576);
  float* z_e = (float*)(ws + 1052672);
  float* dbuf = (float*)(ws + 1052672);

  float* xrec = (float*)d_out;         // 524288 floats
  float* zq = (float*)d_out + 524288;  // 8388608 floats

  prep_k<<<1024, 256, 0, stream>>>(cb, cbt, cnorm);
  conv12_k<<<dim3(64, 8, 2), 256, 0, stream>>>(x, e1w, e1b, e2w, e2b, z_e);
  vq_k<<<dim3(64, 8), 256, 0, stream>>>(z_e, cb, cbt, cnorm, zq);
  convt1_k<<<dim3(16, 8, 8), 256, 0, stream>>>(zq, d1w, d1b, dbuf);
  convt2_k<<<512, 256, 0, stream>>>(dbuf, d2w, d2b, xrec);
}

// Round 18
// 2691.985 us; speedup vs baseline: 1.1518x; 1.1518x over previous
//
#include <hip/hip_runtime.h>
#include <hip/hip_bf16.h>

// ---------------------------------------------------------------------------
// K0: prep: cbt[d][j] = cb[j][d] (transpose), cnorm[j] = numpy-fp32 sum cb[j][d]^2
// (byte-identical to the R6..R12 passing version)
// ---------------------------------------------------------------------------
__global__ __launch_bounds__(256) void prep_k(const float* __restrict__ cb,
                                              float* __restrict__ cbt,
                                              float* __restrict__ cnorm) {
  __shared__ float sv[256];
  int j = blockIdx.x, c = threadIdx.x;
  float v = cb[j * 256 + c];
  cbt[c * 1024 + j] = v;
  sv[c] = v;
  __syncthreads();
  if (c == 0) {
#pragma clang fp contract(off)
    float halves[2];
    for (int h = 0; h < 2; h++) {
      const float* a = sv + h * 128;
      float r[8];
      for (int k = 0; k < 8; k++) r[k] = a[k] * a[k];
      for (int i0 = 8; i0 < 128; i0 += 8)
        for (int k = 0; k < 8; k++) {
          float z = a[i0 + k];
          r[k] += z * z;
        }
      halves[h] = ((r[0] + r[1]) + (r[2] + r[3])) + ((r[4] + r[5]) + (r[6] + r[7]));
    }
    cnorm[j] = halves[0] + halves[1];
  }
}

// ---------------------------------------------------------------------------
// K1: conv1+conv2 — R11 2x2-quad version (measured 1417us, VALUBusy 73%,
// VGPR 104, conflicts 7.6e7). REVERTED byte-identical to the R16 passing
// build. R17 lesson: the T14 stage-split cost +48 VGPR (-> 152, past the
// 128 cliff, occupancy 21->12%, dur 1784). Immediate-write staging IS the
// register-feasible optimum here; do not re-split without proving <=128.
// ---------------------------------------------------------------------------
__global__ __launch_bounds__(256) void conv12_k(const float* __restrict__ x,
                                                const float* __restrict__ w1,
                                                const float* __restrict__ b1,
                                                const float* __restrict__ w2,
                                                const float* __restrict__ b2,
                                                float* __restrict__ z_e) {
  __shared__ float xt[38][40];     // x tile (fp32, zero-padded), 38x38 used
  __shared__ float sp[2][18][20];  // conv1 output tile (18x18 used), dbuf
  __shared__ float sw[2][2176];    // conv2 weights: 16 grp x 8 co x 16, stride 136
  int t = threadIdx.x;
  int b = blockIdx.y;
  int co0 = blockIdx.z * 128;      // co half
  int oh0 = (blockIdx.x >> 3) * 8, ow0 = (blockIdx.x & 7) * 8;  // 8x8 tile
  int ihb = 2 * oh0 - 1, iwb = 2 * ow0 - 1;
  int xrb = 2 * ihb - 1, xcb = 2 * iwb - 1;
  int pg = t & 15, cog = t >> 4;   // pg: 4x4 grid of 2x2-output quads
  int qy = pg >> 2, qx = pg & 3;
  int prow0 = 4 * qy, pcol0 = 4 * qx;  // p-window base in sp (16B-aligned col)

  // sp staging points: 18x18 = 324; thread t handles t, and t+256 if t<68
  int r0s = t / 18, c0s = t - r0s * 18;
  bool has1 = (t < 68);
  int i1 = t + 256;
  int r1s = i1 / 18, c1s = i1 - r1s * 18;
  bool inb0 = (ihb + r0s >= 0) && (ihb + r0s < 128) && (iwb + c0s >= 0) && (iwb + c0s < 128);
  bool inb1 = has1 && (ihb + r1s >= 0) && (ihb + r1s < 128) && (iwb + c1s >= 0) && (iwb + c1s < 128);

  // w2 staging role: two threads per co row (8 floats each), 128 co
  int scl = t >> 1;                 // co_local 0..127
  int shalf = t & 1;                // which 8-tap half
  int sw_off = (scl >> 3) * 136 + (scl & 7) * 16 + shalf * 8;
  const float* w2base = w2 + ((co0 + scl) * 256) * 16 + shalf * 8;

  // ---- stage x tile (38x38 used) ----
  const float* xb = x + b * 65536;
  for (int i = t; i < 1444; i += 256) {
    int rr = i / 38, cc = i - rr * 38;
    int gr = xrb + rr, gc = xcb + cc;
    float v = 0.f;
    if (gr >= 0 && gr < 256 && gc >= 0 && gc < 256) v = xb[gr * 256 + gc];
    xt[rr][cc] = v;
  }
  __syncthreads();

  // stage ci into buffer bf (immediate LDS writes; bf is the dbuf half not
  // being computed from this iteration — consumed before the last barrier)
  auto stage = [&](int ci, int bf) {
    const float4* src = (const float4*)(w2base + ci * 16);
    float4 q0 = src[0];
    float4 q1 = src[1];
    {
      float w1v[16];  // lane-uniform -> scalar regs
#pragma unroll
      for (int k = 0; k < 16; k++) w1v[k] = w1[ci * 16 + k];
      float b1v = b1[ci];
      {
        float a = b1v;
#pragma unroll
        for (int kh = 0; kh < 4; kh++)
#pragma unroll
          for (int kw = 0; kw < 4; kw++)
            a += xt[2 * r0s + kh][2 * c0s + kw] * w1v[kh * 4 + kw];
        sp[bf][r0s][c0s] = inb0 ? fmaxf(a, 0.f) : 0.f;
      }
      if (has1) {
        float a = b1v;
#pragma unroll
        for (int kh = 0; kh < 4; kh++)
#pragma unroll
          for (int kw = 0; kw < 4; kw++)
            a += xt[2 * r1s + kh][2 * c1s + kw] * w1v[kh * 4 + kw];
        sp[bf][r1s][c1s] = inb1 ? fmaxf(a, 0.f) : 0.f;
      }
    }
    float4* dst = (float4*)&sw[bf][sw_off];
    dst[0] = q0;
    dst[1] = q1;
  };

  float accO[8][4];
#pragma unroll
  for (int i = 0; i < 8; i++)
#pragma unroll
    for (int e = 0; e < 4; e++) accO[i][e] = 0.f;

  // prologue: stage ci=0 into buffer 0
  stage(0, 0);
  __syncthreads();

  for (int cio = 0; cio < 16; cio++) {
    float accI[8][4];
#pragma unroll
    for (int i = 0; i < 8; i++)
#pragma unroll
      for (int e = 0; e < 4; e++) accI[i][e] = 0.f;
    for (int cii = 0; cii < 16; cii++) {
      int ci = cio * 16 + cii;
      int cur = ci & 1;
      if (ci < 255) stage(ci + 1, cur ^ 1);  // stage next ci (other dbuf half)
      // ---- this quad's input patch: sp rows prow0..+5, cols pcol0..+5 ----
      float p[6][6];
#pragma unroll
      for (int rr = 0; rr < 6; rr++) {
        float4 v0 = *(const float4*)&sp[cur][prow0 + rr][pcol0];      // 16B-aligned
        float2 v1 = *(const float2*)&sp[cur][prow0 + rr][pcol0 + 4];  // 8B-aligned
        p[rr][0] = v0.x; p[rr][1] = v0.y; p[rr][2] = v0.z; p[rr][3] = v0.w;
        p[rr][4] = v1.x; p[rr][5] = v1.y;
      }
#pragma unroll
      for (int cc = 0; cc < 8; cc++) {
        const float4* wq = (const float4*)&sw[cur][cog * 136 + cc * 16];
        float s00 = 0.f, s01 = 0.f, s10 = 0.f, s11 = 0.f;
#pragma unroll
        for (int kh = 0; kh < 4; kh++) {
          float4 w4 = wq[kh];
          // per-output tap order: kh outer, kw inner (original sequence)
          s00 += p[kh][0] * w4.x;
          s00 += p[kh][1] * w4.y;
          s00 += p[kh][2] * w4.z;
          s00 += p[kh][3] * w4.w;
          s01 += p[kh][2] * w4.x;
          s01 += p[kh][3] * w4.y;
          s01 += p[kh][4] * w4.z;
          s01 += p[kh][5] * w4.w;
          s10 += p[kh + 2][0] * w4.x;
          s10 += p[kh + 2][1] * w4.y;
          s10 += p[kh + 2][2] * w4.z;
          s10 += p[kh + 2][3] * w4.w;
          s11 += p[kh + 2][2] * w4.x;
          s11 += p[kh + 2][3] * w4.y;
          s11 += p[kh + 2][4] * w4.z;
          s11 += p[kh + 2][5] * w4.w;
        }
        accI[cc][0] += s00;
        accI[cc][1] += s01;
        accI[cc][2] += s10;
        accI[cc][3] += s11;
      }
      __syncthreads();  // single barrier per ci-step
    }
#pragma unroll
    for (int cc = 0; cc < 8; cc++)
#pragma unroll
      for (int e = 0; e < 4; e++) accO[cc][e] += accI[cc][e];
  }

  // ---- write z_e (fp32, exact) to global ws ----
#pragma unroll
  for (int cc = 0; cc < 8; cc++) {
    int co = co0 + cog * 8 + cc;
    float bv = b2[co];
    float* zeb = z_e + (b * 256 + co) * 4096;
#pragma unroll
    for (int dy = 0; dy < 2; dy++)
#pragma unroll
      for (int dx = 0; dx < 2; dx++) {
        int oh = oh0 + 2 * qy + dy, ow = ow0 + 2 * qx + dx;
        zeb[oh * 64 + ow] = fmaxf(accO[cc][dy * 2 + dx] + bv, 0.f);
      }
  }
}

// ---------------------------------------------------------------------------
// K2: VQ standalone (byte-identical to R12's passing vq_k).
// ---------------------------------------------------------------------------
__global__ __launch_bounds__(256) void vq_k(const float* __restrict__ z_e,
                                            const float* __restrict__ cb,
                                            const float* __restrict__ cbt,
                                            const float* __restrict__ cnorm,
                                            float* __restrict__ zq) {
  __shared__ float ztT[256][64];
  int t = threadIdx.x;
  int b = blockIdx.y;
  int hw0 = blockIdx.x * 64;
  int lane = t & 63, pg = t >> 6, pbase = pg * 16;

  // ---- fill ztT[d][p] from z_e (coalesced) ----
  const float* zb = z_e + b * 1048576;
  for (int k = 0; k < 64; k++) {
    int dd = pg * 64 + k;
    ztT[dd][lane] = zb[dd * 4096 + hw0 + lane];
  }
  __syncthreads();

  // ---- znorm: numpy pairwise fp32 sum of z^2, point = lane ----
  float myzn;
  {
#pragma clang fp contract(off)
    float halves[2];
    for (int h = 0; h < 2; h++) {
      int base = h * 128;
      float r[8];
#pragma unroll
      for (int k = 0; k < 8; k++) {
        float z = ztT[base + k][lane];
        r[k] = z * z;
      }
      for (int i0 = 8; i0 < 128; i0 += 8)
#pragma unroll
        for (int k = 0; k < 8; k++) {
          float z = ztT[base + i0 + k][lane];
          r[k] += z * z;
        }
      halves[h] = ((r[0] + r[1]) + (r[2] + r[3])) + ((r[4] + r[5]) + (r[6] + r[7]));
    }
    myzn = halves[0] + halves[1];
  }
  float znp[16];
#pragma unroll
  for (int i = 0; i < 16; i++) znp[i] = __shfl(myzn, pbase + i, 64);

  // ---- VQ scores: 2 codes/lane/pass x 8 passes; fp32 absorbed formula ----
  float best[16];
  int bidx[16];
#pragma unroll
  for (int i = 0; i < 16; i++) {
    best[i] = 3.4e38f;
    bidx[i] = 0;
  }
  for (int pass = 0; pass < 8; pass++) {
    int j1 = pass * 128 + lane;
    float a1[16], a2[16];
#pragma unroll
    for (int i = 0; i < 16; i++) {
      a1[i] = 0.f;
      a2[i] = 0.f;
    }
    for (int d0 = 0; d0 < 256; d0 += 8) {
      float c1[8], c2[8];
#pragma unroll
      for (int k = 0; k < 8; k++) {
        c1[k] = cbt[(d0 + k) * 1024 + j1];
        c2[k] = cbt[(d0 + k) * 1024 + j1 + 64];
      }
#pragma unroll
      for (int i = 0; i < 16; i++) {
        int pp = pbase + i;
#pragma unroll
        for (int k = 0; k < 8; k++) {
          float z = ztT[d0 + k][pp];
          a1[i] = __builtin_fmaf(z, c1[k], a1[i]);
          a2[i] = __builtin_fmaf(z, c2[k], a2[i]);
        }
      }
    }
    float cn1 = cnorm[j1], cn2 = cnorm[j1 + 64];
    {
#pragma clang fp contract(off)
#pragma unroll
      for (int i = 0; i < 16; i++) {
        float t1 = znp[i] - 2.0f * a1[i];
        float s1 = t1 + cn1;
        if (s1 < best[i]) {
          best[i] = s1;
          bidx[i] = j1;
        }
        float t2 = znp[i] - 2.0f * a2[i];
        float s2 = t2 + cn2;
        if (s2 < best[i]) {
          best[i] = s2;
          bidx[i] = j1 + 64;
        }
      }
    }
  }
#pragma unroll
  for (int off = 1; off < 64; off <<= 1) {
#pragma unroll
    for (int i = 0; i < 16; i++) {
      float ov = __shfl_xor(best[i], off, 64);
      int oi = __shfl_xor(bidx[i], off, 64);
      if (ov < best[i] || (ov == best[i] && oi < bidx[i])) {
        best[i] = ov;
        bidx[i] = oi;
      }
    }
  }
  __syncthreads();
  int* sidx = (int*)&ztT[0][0];
  if (lane == 0) {
#pragma unroll
    for (int i = 0; i < 16; i++) sidx[pbase + i] = bidx[i];
  }
  __syncthreads();

  // ---- gather z_q: exact fp32 codebook rows (coalesced writes) ----
  int p = t & 63, c4 = t >> 6;
  int jw = sidx[p];
  float* zqb = zq + b * 1048576;
  for (int k = 0; k < 64; k++) {
    int c = c4 * 64 + k;
    zqb[c * 4096 + hw0 + p] = cb[jw * 256 + c];
  }
}

// ---------------------------------------------------------------------------
// K3: convT1 — R16 version, byte-identical (best: dropped below 1417us).
// LDS inputs + LDS broadcast weights, direct-quad FMAs (no wv[16] copy),
// __launch_bounds__(256,2): 128 arch + 128 acc = 256/wave = 2 waves/SIMD.
// DO NOT add registers here — zero headroom under the forced bound.
// ---------------------------------------------------------------------------
__global__ __launch_bounds__(256, 2) void convt1_k(const float* __restrict__ zq,
                                                   const float* __restrict__ w,
                                                   const float* __restrict__ bias,
                                                   float* __restrict__ d) {
  __shared__ float zt[2][18][20];  // zq tile dbuf (18x18 used, pad 20)
  __shared__ float sw[2][512];     // weights dbuf: 32 co x 16 taps
  int t = threadIdx.x;
  int b = blockIdx.z;
  int co0 = blockIdx.y * 32;
  int oh0 = (blockIdx.x >> 2) * 32, ow0 = (blockIdx.x & 3) * 32;
  int wid8 = __builtin_amdgcn_readfirstlane(t >> 6) * 8;
  int lane = t & 63;
  int ty = lane >> 3, tx = lane & 7;
  int ihb = oh0 / 2 - 1, iwb = ow0 / 2 - 1;  // tile covers input rows ihb..ihb+17
  const float* zqb = zq + b * 1048576;

  // staging points: 18x18 = 324; thread t handles t, and t+256 if t<68
  int r0s = t / 18, c0s = t - r0s * 18;
  bool has1 = (t < 68);
  int i1 = t + 256;
  int r1s = i1 / 18, c1s = i1 - r1s * 18;
  int g0r = ihb + r0s, g0c = iwb + c0s;
  int g1r = ihb + r1s, g1c = iwb + c1s;
  bool ok0 = (g0r >= 0) && (g0r < 64) && (g0c >= 0) && (g0c < 64);
  bool ok1 = has1 && (g1r >= 0) && (g1r < 64) && (g1c >= 0) && (g1c < 64);
  int off0 = g0r * 64 + g0c, off1 = g1r * 64 + g1c;

  auto stage = [&](int ci, int bf) {
    const float* zc = zqb + ci * 4096;
    zt[bf][r0s][c0s] = ok0 ? zc[off0] : 0.f;
    if (has1) zt[bf][r1s][c1s] = ok1 ? zc[off1] : 0.f;
    if (t < 128) {
      const float4* wsrc = (const float4*)(w + (ci * 256 + co0) * 16);
      *((float4*)&sw[bf][t * 4]) = wsrc[t];
    }
  };

  float acc[8][16];
#pragma unroll
  for (int i = 0; i < 8; i++)
#pragma unroll
    for (int e = 0; e < 16; e++) acc[i][e] = 0.f;

  stage(0, 0);
  __syncthreads();

  for (int ci = 0; ci < 256; ci++) {
    int cur = ci & 1;
    if (ci < 255) stage(ci + 1, cur ^ 1);  // stage next ci (other dbuf half)
    // ---- this lane's input patch from LDS: rows 2ty.., cols 2tx.. ----
    float p[4][4];
#pragma unroll
    for (int r = 0; r < 4; r++)
#pragma unroll
      for (int c = 0; c < 4; c++)
        p[r][c] = zt[cur][2 * ty + r][2 * tx + c];
#pragma unroll
    for (int cc = 0; cc < 8; cc++) {
      // wave-uniform LDS address -> broadcast b128 reads, conflict-free
      const float4* wq = (const float4*)&sw[cur][(wid8 + cc) * 16];
      float4 q0 = wq[0], q1 = wq[1], q2 = wq[2], q3 = wq[3];
#pragma unroll
      for (int dy = 0; dy < 4; dy++) {
        int rA = ((dy + 1) >> 1) + 1, rB = rA - 1;
        // khA = 1-(dy&1): quad q1 (dy even) or q0 (dy odd); khB = khA+2
        float4 qA = (dy & 1) ? q0 : q1;
        float4 qB = (dy & 1) ? q2 : q3;
#pragma unroll
        for (int dx = 0; dx < 4; dx++) {
          int cA = ((dx + 1) >> 1) + 1, cB = cA - 1;
          // kwA = 1-(dx&1): comp .y (dx even) or .x (dx odd); kwB = kwA+2
          float wAA = (dx & 1) ? qA.x : qA.y;
          float wAB = (dx & 1) ? qA.z : qA.w;
          float wBA = (dx & 1) ? qB.x : qB.y;
          float wBB = (dx & 1) ? qB.z : qB.w;
          float s = p[rA][cA] * wAA;
          s += p[rA][cB] * wAB;
          s += p[rB][cA] * wBA;
          s += p[rB][cB] * wBB;
          acc[cc][dy * 4 + dx] += s;
        }
      }
    }
    __syncthreads();  // stage-writes for ci+1 complete before next read
  }
#pragma unroll
  for (int cc = 0; cc < 8; cc++) {
    int co = co0 + wid8 + cc;
    float bv = bias[co];
    float* db = d + (b * 256 + co) * 16384;
#pragma unroll
    for (int dy = 0; dy < 4; dy++)
#pragma unroll
      for (int dx = 0; dx < 4; dx++) {
        int oh = oh0 + 4 * ty + dy, ow = ow0 + 4 * tx + dx;
        db[oh * 128 + ow] = fmaxf(acc[cc][dy * 4 + dx] + bv, 0.f);
      }
  }
}

// ---------------------------------------------------------------------------
// K4: convT2 FULL BATCH — 2x2-tile version (grid 512), byte-identical to the
// R11 passing build.
// ---------------------------------------------------------------------------
__global__ __launch_bounds__(256) void convt2_k(const float* __restrict__ d,
                                                const float* __restrict__ w,
                                                const float* __restrict__ bias,
                                                float* __restrict__ out) {
  int idx = blockIdx.x * 256 + threadIdx.x;  // < 131072
  int j = idx & 127;          // ow / 2
  int i = (idx >> 7) & 127;   // oh / 2
  int b = idx >> 14;
  bool rT = (i > 0), rB = (i < 127), cL = (j > 0), cR = (j < 127);
  const float* db = d + b * 4194304;
  int r0 = (i - 1) * 128 + j, r1 = i * 128 + j, r2 = (i + 1) * 128 + j;
  float bv = bias[0];
  float a00 = bv, a01 = bv, a10 = bv, a11 = bv;
#pragma unroll 2
  for (int ci = 0; ci < 256; ci++) {
    const float* dc = db + ci * 16384;
    const float* wc = w + ci * 16;  // wave-uniform -> SGPRs
    float p11 = dc[r1];
    float p10 = cL ? dc[r1 - 1] : 0.f;
    float p12 = cR ? dc[r1 + 1] : 0.f;
    float p01 = rT ? dc[r0] : 0.f;
    float p00 = (rT && cL) ? dc[r0 - 1] : 0.f;
    float p02 = (rT && cR) ? dc[r0 + 1] : 0.f;
    float p21 = rB ? dc[r2] : 0.f;
    float p20 = (rB && cL) ? dc[r2 - 1] : 0.f;
    float p22 = (rB && cR) ? dc[r2 + 1] : 0.f;
    float wv[16];
#pragma unroll
    for (int k = 0; k < 16; k++) wv[k] = wc[k];
    // (oh=2i, ow=2j):   khA=1 khB=3 kwA=1 kwB=3; A-row=i, B-row=i-1
    {
      float s = 0.f;
      s += p11 * wv[5];
      if (cL) s += p10 * wv[7];
      if (rT) s += p01 * wv[13];
      if (rT && cL) s += p00 * wv[15];
      a00 += s;
    }
    // (oh=2i, ow=2j+1): khA=1 khB=3 kwA=0 kwB=2; A-col=j+1, B-col=j
    {
      float s = 0.f;
      if (cR) s += p12 * wv[4];
      s += p11 * wv[6];
      if (rT && cR) s += p02 * wv[12];
      if (rT) s += p01 * wv[14];
      a01 += s;
    }
    // (oh=2i+1, ow=2j): khA=0 khB=2 kwA=1 kwB=3; A-row=i+1, B-row=i
    {
      float s = 0.f;
      if (rB) s += p21 * wv[1];
      if (rB && cL) s += p20 * wv[3];
      s += p11 * wv[9];
      if (cL) s += p10 * wv[11];
      a10 += s;
    }
    // (oh=2i+1, ow=2j+1): khA=0 khB=2 kwA=0 kwB=2
    {
      float s = 0.f;
      if (rB && cR) s += p22 * wv[0];
      if (rB) s += p21 * wv[2];
      if (cR) s += p12 * wv[8];
      s += p11 * wv[10];
      a11 += s;
    }
  }
  int ob = b * 65536 + (2 * i) * 256 + 2 * j;
  *(float2*)&out[ob] = make_float2(a00, a01);
  *(float2*)&out[ob + 256] = make_float2(a10, a11);
}

// ---------------------------------------------------------------------------
extern "C" void kernel_launch(void* const* d_in, const int* in_sizes, int n_in,
                              void* d_out, int out_size, void* d_ws, size_t ws_size,
                              hipStream_t stream) {
  const float* x = (const float*)d_in[0];
  const float* e1w = (const float*)d_in[1];
  const float* e1b = (const float*)d_in[2];
  const float* e2w = (const float*)d_in[3];
  const float* e2b = (const float*)d_in[4];
  const float* cb = (const float*)d_in[5];
  const float* d1w = (const float*)d_in[6];
  const float* d1b = (const float*)d_in[7];
  const float* d2w = (const float*)d_in[8];
  const float* d2b = (const float*)d_in[9];

  // ws layout (135,270,400 B total — same proven footprint as R6..R12):
  //   cbt   fp32 [0, 1048576)              codebook transpose [d][j]
  //   cnorm fp32 [1048576, 1052672)        numpy-fp32 |c_j|^2
  //   z_e   fp32 [1052672, 34607104)       encoder output (dead after vq_k)
  //   dbuf  fp32 [1052672, 135270400)      decoder intermediate (OVERLAPS z_e;
  //                                        written by convt1_k after vq_k)
  char* ws = (char*)d_ws;
  float* cbt = (float*)ws;
  float* cnorm = (float*)(ws + 1048576);
  float* z_e = (float*)(ws + 1052672);
  float* dbuf = (float*)(ws + 1052672);

  float* xrec = (float*)d_out;         // 524288 floats
  float* zq = (float*)d_out + 524288;  // 8388608 floats

  prep_k<<<1024, 256, 0, stream>>>(cb, cbt, cnorm);
  conv12_k<<<dim3(64, 8, 2), 256, 0, stream>>>(x, e1w, e1b, e2w, e2b, z_e);
  vq_k<<<dim3(64, 8), 256, 0, stream>>>(z_e, cb, cbt, cnorm, zq);
  convt1_k<<<dim3(16, 8, 8), 256, 0, stream>>>(zq, d1w, d1b, dbuf);
  convt2_k<<<512, 256, 0, stream>>>(dbuf, d2w, d2b, xrec);
}